// Round 3
// baseline (4230.133 us; speedup 1.0000x reference)
//
#include <hip/hip_runtime.h>
#include <hip/hip_bf16.h>

// Problem dims
#define BSZ 32
#define SSZ 512
#define ISZ 512
#define HSZ 512
// ws layout (bytes)
#define XB_OFF   0ull                       // [S][64 kc][32 b][8] ushort (bf16 bits) = 16 MB
#define HEX_OFF  (16ull << 20)              // [2 dir][2 buf][64 kc][32 b][8] ushort = 128 KB
#define CTR_OFF  (HEX_OFF + (128ull << 10)) // flags: [dir] stride 2048 dwords; 32 used per dir
// placement table at dword index 4096 in flags: [2 dir][32 p] = xcc+1

typedef __attribute__((ext_vector_type(8)))  short short8;
typedef __attribute__((ext_vector_type(4)))  float f32x4;
typedef __attribute__((ext_vector_type(4)))  unsigned short us4;
typedef __attribute__((ext_vector_type(4)))  int i32x4;

__device__ __forceinline__ unsigned short f2bf(float f) {
    union { float f; unsigned u; } v; v.f = f;
    unsigned r = v.u + 0x7fffu + ((v.u >> 16) & 1u);   // RNE
    return (unsigned short)(r >> 16);
}

__device__ __forceinline__ float sigf(float x) { return 1.0f / (1.0f + __expf(-x)); }
__device__ __forceinline__ float tanhfast(float x) {
    float a = fabsf(x);
    float e = __expf(-2.0f * a);
    float t = (1.0f - e) / (1.0f + e);
    return x < 0.0f ? -t : t;
}

// X [B][S][I] fp32 -> Xb [t][kc][b][8] bf16-bits (MFMA A-fragment friendly layout)
__global__ void k_xpose(const float* __restrict__ X, unsigned short* __restrict__ Xb) {
    int idx = blockIdx.x * 256 + threadIdx.x;     // 2^21 threads total
    int i4 = idx & 127;                           // float4 index along I
    int t  = (idx >> 7) & 511;
    int b  = idx >> 16;
    float4 v = reinterpret_cast<const float4*>(X)[idx];
    us4 o = { f2bf(v.x), f2bf(v.y), f2bf(v.z), f2bf(v.w) };
    *reinterpret_cast<us4*>(Xb + (size_t)t * 16384 + (size_t)(i4 >> 1) * 256 + b * 8 + (i4 & 1) * 4) = o;
}

__launch_bounds__(256, 1)
__global__ void k_bilstm(const float* __restrict__ Wih_f, const float* __restrict__ Whh_f,
                         const float* __restrict__ bih_f, const float* __restrict__ bhh_f,
                         const float* __restrict__ Wih_b, const float* __restrict__ Whh_b,
                         const float* __restrict__ bih_b, const float* __restrict__ bhh_b,
                         const unsigned short* __restrict__ Xb,
                         unsigned short* h_ex, unsigned* flags, float* __restrict__ out)
{
    const int tid = threadIdx.x;
    const int grp = blockIdx.x & 7;
    if (grp >= 2) return;                // 256 blocks: XCD0 = dir0, XCD1 = dir1
    const int dir  = grp;
    const int p    = blockIdx.x >> 3;    // 0..31 : owns h-cols [16p, 16p+16)
    const int wv   = tid >> 6;
    const int ln   = tid & 63;
    const int isx  = (wv < 2);           // waves 0,1: x-producers; waves 2,3: h-recurrence
    const int nt   = wv & 1;             // x: gate-col half ; h: K-half
    const int q    = ln >> 4;
    const int m15  = ln & 15;

    // publish my XCC_ID for runtime placement verification
    unsigned* tab = flags + 4096;
    {
        unsigned xcc;
        asm volatile("s_getreg_b32 %0, hwreg(20, 0, 32)" : "=s"(xcc));
        if (tid == 0)
            __hip_atomic_store(tab + dir * 32 + p, (xcc & 7u) + 1u,
                               __ATOMIC_RELAXED, __HIP_MEMORY_SCOPE_AGENT);
    }

    const float* Wih = dir ? Wih_b : Wih_f;
    const float* Whh = dir ? Whh_b : Whh_f;
    const float* bi  = dir ? bih_b : bih_f;
    const float* bh  = dir ? bhh_b : bhh_f;

    __shared__ float gates[2][32][67];     // h partial planes (K-half 0 / 1)
    __shared__ float fifo[4][32][67];      // x-gate tile ring: slot = step & 3
    __shared__ float cst[32][16];
    __shared__ float outbuf[2][32][16];    // double-buffered h (fp32) for deferred out
    __shared__ float bias[64];
    __shared__ int   mode_sh;

    // ---- weights in registers for all 512 steps (128 VGPRs either role) ----
    short8 breg[32];
    if (isx) {
        // x-wave: 2 gate groups (nt*2, nt*2+1), full K=512 -> breg[ks*2+gg], ks 0..15
#pragma unroll
        for (int ks = 0; ks < 16; ++ks)
#pragma unroll
            for (int gg = 0; gg < 2; ++gg) {
                const float* wr = Wih + (size_t)((nt * 2 + gg) * 512 + p * 16 + m15) * 512
                                      + ks * 32 + q * 8;
                short8 bb;
#pragma unroll
                for (int j = 0; j < 8; ++j) bb[j] = (short)f2bf(wr[j]);
                breg[ks * 2 + gg] = bb;
            }
    } else {
        // h-wave: all 4 gate groups, K-half nt -> breg[ks*4+g], ks 0..7
#pragma unroll
        for (int ks = 0; ks < 8; ++ks)
#pragma unroll
            for (int g = 0; g < 4; ++g) {
                const float* wr = Whh + (size_t)(g * 512 + p * 16 + m15) * 512
                                      + nt * 256 + ks * 32 + q * 8;
                short8 bb;
#pragma unroll
                for (int j = 0; j < 8; ++j) bb[j] = (short)f2bf(wr[j]);
                breg[ks * 4 + g] = bb;
            }
    }

    if (tid < 64) {
        int c = tid;
        int gr = (c >> 4) * 512 + p * 16 + (c & 15);
        bias[c] = bi[gr] + bh[gr];
    }
    for (int i = tid; i < 512; i += 256) ((float*)cst)[i] = 0.0f;

    // ---- placement discovery (deadlock-free: every owner writes its slot) ----
    if (tid < 64) {
        const unsigned* tp = tab + dir * 32 + (tid & 31);
        unsigned v;
        do { v = __hip_atomic_load(tp, __ATOMIC_RELAXED, __HIP_MEMORY_SCOPE_AGENT); } while (v == 0u);
        unsigned ref = __shfl(v, 0);
        int same = (__ballot(v == ref) == ~0ull) ? 1 : 0;
        if (tid == 0) mode_sh = same;
    }
    __syncthreads();
    const int fast = mode_sh;

    unsigned* flg = flags + (size_t)dir * 2048;
    unsigned short* hexd = h_ex + (size_t)dir * 2 * 16384;

    // ---- x producer: compute x-gate tile for step sp into fifo[sp&3] ----
    auto produce = [&](int sp) {
        int t = dir ? (511 - sp) : sp;
        const unsigned short* abase = Xb + (size_t)t * 16384;
        f32x4 xa[2][2];
#pragma unroll
        for (int gg = 0; gg < 2; ++gg) { xa[gg][0] = {0.f,0.f,0.f,0.f}; xa[gg][1] = {0.f,0.f,0.f,0.f}; }
#pragma unroll
        for (int ks = 0; ks < 16; ++ks) {
            const unsigned short* ap = abase + (ks * 4 + q) * 256 + m15 * 8;
            short8 a0 = *reinterpret_cast<const short8*>(ap);
            short8 a1 = *reinterpret_cast<const short8*>(ap + 128);
#pragma unroll
            for (int gg = 0; gg < 2; ++gg) {
                xa[gg][0] = __builtin_amdgcn_mfma_f32_16x16x32_bf16(a0, breg[ks * 2 + gg], xa[gg][0], 0, 0, 0);
                xa[gg][1] = __builtin_amdgcn_mfma_f32_16x16x32_bf16(a1, breg[ks * 2 + gg], xa[gg][1], 0, 0, 0);
            }
        }
        float (*fp)[67] = fifo[sp & 3];
#pragma unroll
        for (int gg = 0; gg < 2; ++gg)
#pragma unroll
            for (int r = 0; r < 4; ++r) {
                fp[q * 4 + r][(nt * 2 + gg) * 16 + m15]      = xa[gg][0][r];
                fp[16 + q * 4 + r][(nt * 2 + gg) * 16 + m15] = xa[gg][1][r];
            }
    };

    // ---- prologue: x-waves pre-fill fifo slots for steps 0..2 ----
    if (isx) { produce(0); produce(1); produce(2); }

    int agent_poll = 0;

    for (int s = 0; s < 512; ++s) {
        if (isx) {
            // -- deferred out store for step s-1 (off everyone's critical path) --
            if (s > 0) {
                int pt = dir ? (512 - s) : (s - 1);
                int L = nt * 64 + ln; int b = L >> 2; int qd = L & 3;
                f32x4 hvv = *reinterpret_cast<const f32x4*>(&outbuf[(s - 1) & 1][b][qd * 4]);
                *reinterpret_cast<f32x4*>(&out[(size_t)b * 524288 + (size_t)pt * 1024
                                               + dir * 512 + p * 16 + qd * 4]) = hvv;
            }
            // -- produce x tile for step s+3 (3 steps ahead of its consumer) --
            if (s + 3 < 512) produce(s + 3);
        } else {
            // -------- h-recurrence (the per-step critical path) --------
            f32x4 acc[4][2];
#pragma unroll
            for (int g = 0; g < 4; ++g) { acc[g][0] = {0.f,0.f,0.f,0.f}; acc[g][1] = {0.f,0.f,0.f,0.f}; }

            if (fast) {
                if (s > 0) {
                    const unsigned* fp = flg + (ln & 31);
                    if (!agent_poll) {
                        int spins = 0;
                        for (;;) {
                            unsigned v;
                            asm volatile("global_load_dword %0, %1, off sc0\n\t"
                                         "s_waitcnt vmcnt(0)"
                                         : "=&v"(v) : "v"(fp) : "memory");
                            if (__ballot((int)(v >= (unsigned)s)) == ~0ull) break;
                            if (++spins > 20000) { agent_poll = 1; break; }
                        }
                    }
                    if (agent_poll) {
                        for (;;) {
                            unsigned v = __hip_atomic_load(fp, __ATOMIC_RELAXED, __HIP_MEMORY_SCOPE_AGENT);
                            if (__ballot((int)(v >= (unsigned)s)) == ~0ull) break;
                        }
                    }
                    asm volatile("" ::: "memory");
                }
                const unsigned short* ab = hexd + (size_t)((s + 1) & 1) * 16384 + nt * 8192;
                i32x4 A0[8], A1[8];
#pragma unroll
                for (int ks = 0; ks < 8; ++ks) {
                    const unsigned short* ap = ab + (ks * 4 + q) * 256 + m15 * 8;
                    asm volatile("global_load_dwordx4 %0, %2, off sc0\n\t"
                                 "global_load_dwordx4 %1, %3, off sc0"
                                 : "=&v"(A0[ks]), "=&v"(A1[ks])
                                 : "v"(ap), "v"(ap + 128) : "memory");
                }
#pragma unroll
                for (int ks = 0; ks < 8; ++ks) {
                    asm volatile("s_waitcnt vmcnt(%0)" :: "n"(14 - 2 * ks) : "memory");
                    __builtin_amdgcn_sched_barrier(0);
                    short8 a0 = __builtin_bit_cast(short8, A0[ks]);
                    short8 a1 = __builtin_bit_cast(short8, A1[ks]);
#pragma unroll
                    for (int g = 0; g < 4; ++g) {
                        acc[g][0] = __builtin_amdgcn_mfma_f32_16x16x32_bf16(a0, breg[ks * 4 + g], acc[g][0], 0, 0, 0);
                        acc[g][1] = __builtin_amdgcn_mfma_f32_16x16x32_bf16(a1, breg[ks * 4 + g], acc[g][1], 0, 0, 0);
                    }
                }
            } else {
                // fallback agent/LLC path
                if (s > 0) {
                    const unsigned* fp = flg + (ln & 31);
                    for (;;) {
                        unsigned v = __hip_atomic_load(fp, __ATOMIC_RELAXED, __HIP_MEMORY_SCOPE_AGENT);
                        if (__ballot((int)(v >= (unsigned)s)) == ~0ull) break;
                    }
                    asm volatile("" ::: "memory");
                }
                const unsigned* abase = reinterpret_cast<const unsigned*>(hexd + (size_t)((s + 1) & 1) * 16384);
#pragma unroll
                for (int ks = 0; ks < 8; ++ks) {
                    const unsigned* ap = abase + ((nt * 32 + ks * 4 + q) * 256 + m15 * 8) / 2;
                    union { short8 s8; unsigned u[4]; } ua0, ua1;
#pragma unroll
                    for (int w = 0; w < 4; ++w) {
                        ua0.u[w] = __hip_atomic_load(ap + w,      __ATOMIC_RELAXED, __HIP_MEMORY_SCOPE_AGENT);
                        ua1.u[w] = __hip_atomic_load(ap + 64 + w, __ATOMIC_RELAXED, __HIP_MEMORY_SCOPE_AGENT);
                    }
#pragma unroll
                    for (int g = 0; g < 4; ++g) {
                        acc[g][0] = __builtin_amdgcn_mfma_f32_16x16x32_bf16(ua0.s8, breg[ks * 4 + g], acc[g][0], 0, 0, 0);
                        acc[g][1] = __builtin_amdgcn_mfma_f32_16x16x32_bf16(ua1.s8, breg[ks * 4 + g], acc[g][1], 0, 0, 0);
                    }
                }
            }

            // dump h partials (plane nt); C/D: col = ln&15, row = q*4 + r
#pragma unroll
            for (int g = 0; g < 4; ++g)
#pragma unroll
                for (int r = 0; r < 4; ++r) {
                    gates[nt][q * 4 + r][g * 16 + m15]      = acc[g][0][r];
                    gates[nt][16 + q * 4 + r][g * 16 + m15] = acc[g][1][r];
                }
        }

        asm volatile("s_waitcnt lgkmcnt(0)" ::: "memory");
        __builtin_amdgcn_s_barrier();    // sync#1: h dumps (and fifo slot s+3) visible

        // ---- gate math: all 256 threads, (b, j0) and (b, j0+1) ----
        {
            const float (*xp)[67] = fifo[s & 3];
            int b  = tid >> 3;
            int j0 = (tid & 7) * 2;
            float hv01[2];
#pragma unroll
            for (int u = 0; u < 2; ++u) {
                int j = j0 + u;
                float ig = gates[0][b][j]      + gates[1][b][j]      + xp[b][j]      + bias[j];
                float fg = gates[0][b][16 + j] + gates[1][b][16 + j] + xp[b][16 + j] + bias[16 + j];
                float gg = gates[0][b][32 + j] + gates[1][b][32 + j] + xp[b][32 + j] + bias[32 + j];
                float og = gates[0][b][48 + j] + gates[1][b][48 + j] + xp[b][48 + j] + bias[48 + j];
                float cn = sigf(fg) * cst[b][j] + sigf(ig) * tanhfast(gg);
                cst[b][j] = cn;
                hv01[u] = sigf(og) * tanhfast(cn);
            }
            *reinterpret_cast<float2*>(&outbuf[s & 1][b][j0]) = make_float2(hv01[0], hv01[1]);
            // packed 2xbf16 h store for the next step
            int hc0 = p * 16 + j0;
            unsigned pk = (unsigned)f2bf(hv01[0]) | ((unsigned)f2bf(hv01[1]) << 16);
            unsigned* dst = reinterpret_cast<unsigned*>(
                hexd + (size_t)(s & 1) * 16384 + (size_t)(hc0 >> 3) * 256 + b * 8 + (hc0 & 7));
            if (fast) {
                asm volatile("global_store_dword %0, %1, off sc0" :: "v"(dst), "v"(pk) : "memory");
            } else {
                __hip_atomic_store(dst, pk, __ATOMIC_RELAXED, __HIP_MEMORY_SCOPE_AGENT);
            }
        }

        // ---- publish: drain h stores (out stores are >1 step old by now) ----
        asm volatile("s_waitcnt vmcnt(0)" ::: "memory");
        asm volatile("s_waitcnt lgkmcnt(0)" ::: "memory");
        __builtin_amdgcn_s_barrier();    // sync#2
        if (tid == 0) {
            if (fast) {
                unsigned sv = (unsigned)(s + 1);
                asm volatile("global_store_dword %0, %1, off sc0" :: "v"(flg + p), "v"(sv) : "memory");
            } else {
                __hip_atomic_store(flg + p, (unsigned)(s + 1), __ATOMIC_RELAXED, __HIP_MEMORY_SCOPE_AGENT);
            }
        }
    }

    // ---- epilogue: step-511 out + final states (x-waves, 128 lanes) ----
    if (isx) {
        int L = nt * 64 + ln; int b = L >> 2; int qd = L & 3;
        int tl = dir ? 0 : 511;
        f32x4 hvv = *reinterpret_cast<const f32x4*>(&outbuf[1][b][qd * 4]);
        *reinterpret_cast<f32x4*>(&out[(size_t)b * 524288 + (size_t)tl * 1024
                                       + dir * 512 + p * 16 + qd * 4]) = hvv;
        *reinterpret_cast<f32x4*>(&out[16777216 + dir * 16384 + b * 512 + p * 16 + qd * 4]) = hvv;
        f32x4 cvv = *reinterpret_cast<const f32x4*>(&cst[b][qd * 4]);
        *reinterpret_cast<f32x4*>(&out[16777216 + 32768 + dir * 16384 + b * 512 + p * 16 + qd * 4]) = cvv;
    }
}

extern "C" void kernel_launch(void* const* d_in, const int* in_sizes, int n_in,
                              void* d_out, int out_size, void* d_ws, size_t ws_size,
                              hipStream_t stream) {
    const float* X     = (const float*)d_in[0];
    const float* Wih_f = (const float*)d_in[1];
    const float* Whh_f = (const float*)d_in[2];
    const float* bih_f = (const float*)d_in[3];
    const float* bhh_f = (const float*)d_in[4];
    const float* Wih_b = (const float*)d_in[5];
    const float* Whh_b = (const float*)d_in[6];
    const float* bih_b = (const float*)d_in[7];
    const float* bhh_b = (const float*)d_in[8];
    float* out = (float*)d_out;

    unsigned short* Xb   = (unsigned short*)((char*)d_ws + XB_OFF);
    unsigned short* h_ex = (unsigned short*)((char*)d_ws + HEX_OFF);
    unsigned*       flg  = (unsigned*)((char*)d_ws + CTR_OFF);

    // zero h_ex (h_{-1}=0) + flags + placement table
    hipMemsetAsync((char*)d_ws + HEX_OFF, 0, (128ull + 64ull) << 10, stream);
    k_xpose<<<8192, 256, 0, stream>>>(X, Xb);
    // 256 blocks (1/CU): round-robin puts (blockIdx&7)==d on XCD d.
    k_bilstm<<<256, 256, 0, stream>>>(Wih_f, Whh_f, bih_f, bhh_f,
                                      Wih_b, Whh_b, bih_b, bhh_b,
                                      Xb, h_ex, flg, out);
}

// Round 4
// 3378.535 us; speedup vs baseline: 1.2521x; 1.2521x over previous
//
#include <hip/hip_runtime.h>
#include <hip/hip_bf16.h>

// Problem dims
#define BSZ 32
#define SSZ 512
#define ISZ 512
#define HSZ 512
// ws layout (bytes)
#define XB_OFF   0ull                       // [S][64 kc][32 b][8] ushort (bf16 bits) = 16 MB
#define HEX_OFF  (16ull << 20)              // [2 dir][2 buf][64 kc][32 b][8] ushort = 128 KB
#define CTR_OFF  (HEX_OFF + (128ull << 10)) // flags: [dir] stride 2048 dwords; 32 used per dir
// placement table at dword index 4096 in flags: [2 dir][32 p] = xcc+1

typedef __attribute__((ext_vector_type(8)))  short short8;
typedef __attribute__((ext_vector_type(4)))  float f32x4;
typedef __attribute__((ext_vector_type(4)))  unsigned short us4;
typedef __attribute__((ext_vector_type(4)))  int i32x4;

__device__ __forceinline__ unsigned short f2bf(float f) {
    union { float f; unsigned u; } v; v.f = f;
    unsigned r = v.u + 0x7fffu + ((v.u >> 16) & 1u);   // RNE
    return (unsigned short)(r >> 16);
}

__device__ __forceinline__ float sigf(float x) { return 1.0f / (1.0f + __expf(-x)); }
__device__ __forceinline__ float tanhfast(float x) {
    float a = fabsf(x);
    float e = __expf(-2.0f * a);
    float t = (1.0f - e) / (1.0f + e);
    return x < 0.0f ? -t : t;
}

// async global->LDS, 16B per lane (wave-uniform LDS base; HW adds lane*16)
__device__ __forceinline__ void dma16(const unsigned short* g, unsigned short* l) {
    __builtin_amdgcn_global_load_lds((const __attribute__((address_space(1))) unsigned int*)(g),
                                     (__attribute__((address_space(3))) unsigned int*)(l), 16, 0, 0);
}

// X [B][S][I] fp32 -> Xb [t][kc][b][8] bf16-bits (MFMA A-fragment friendly layout)
__global__ void k_xpose(const float* __restrict__ X, unsigned short* __restrict__ Xb) {
    int idx = blockIdx.x * 256 + threadIdx.x;     // 2^21 threads total
    int i4 = idx & 127;                           // float4 index along I
    int t  = (idx >> 7) & 511;
    int b  = idx >> 16;
    float4 v = reinterpret_cast<const float4*>(X)[idx];
    us4 o = { f2bf(v.x), f2bf(v.y), f2bf(v.z), f2bf(v.w) };
    *reinterpret_cast<us4*>(Xb + (size_t)t * 16384 + (size_t)(i4 >> 1) * 256 + b * 8 + (i4 & 1) * 4) = o;
}

__launch_bounds__(256, 1)
__global__ void k_bilstm(const float* __restrict__ Wih_f, const float* __restrict__ Whh_f,
                         const float* __restrict__ bih_f, const float* __restrict__ bhh_f,
                         const float* __restrict__ Wih_b, const float* __restrict__ Whh_b,
                         const float* __restrict__ bih_b, const float* __restrict__ bhh_b,
                         const unsigned short* __restrict__ Xb,
                         unsigned short* h_ex, unsigned* flags, float* __restrict__ out)
{
    const int tid = threadIdx.x;
    const int grp = blockIdx.x & 7;
    if (grp >= 2) return;                // 256 blocks: XCD0 = dir0, XCD1 = dir1
    const int dir = grp;
    const int p   = blockIdx.x >> 3;     // 0..31 : owns h-cols [16p, 16p+16)
    const int wv  = tid >> 6;
    const int ln  = tid & 63;
    const int kh  = wv >> 1;             // 0: x-projection, 1: h-recurrence
    const int nt  = wv & 1;              // gate-pair tile (0: i,f ; 1: g,o)
    const int q   = ln >> 4;
    const int m15 = ln & 15;

    // publish my XCC_ID for runtime placement verification
    unsigned* tab = flags + 4096;
    {
        unsigned xcc;
        asm volatile("s_getreg_b32 %0, hwreg(20, 0, 32)" : "=s"(xcc));
        if (tid == 0)
            __hip_atomic_store(tab + dir * 32 + p, (xcc & 7u) + 1u,
                               __ATOMIC_RELAXED, __HIP_MEMORY_SCOPE_AGENT);
    }

    const float* Wsel = kh ? (dir ? Whh_b : Whh_f) : (dir ? Wih_b : Wih_f);
    const float* bi   = dir ? bih_b : bih_f;
    const float* bh   = dir ? bhh_b : bhh_f;

    __shared__ float gates[2][32][67];   // 67: breaks even-bank 4-way conflicts
    __shared__ float cst[32][16];
    __shared__ float outbuf[2][32][16];  // h (fp32) bounce for deferred out stores
    __shared__ float bias[64];
    __shared__ int   mode_sh;
    __shared__ __align__(16) unsigned short xstage[3][16384];  // 3-slot Xb tile ring (32KB each)

    // ---- load B fragments (weights) into registers, kept for all 512 steps ----
    short8 breg[16][2];
    {
        const float* wr0 = Wsel + (size_t)((nt * 2 + 0) * 512 + p * 16 + m15) * 512 + q * 8;
        const float* wr1 = Wsel + (size_t)((nt * 2 + 1) * 512 + p * 16 + m15) * 512 + q * 8;
#pragma unroll
        for (int ks = 0; ks < 16; ++ks) {
            short8 b0, b1;
#pragma unroll
            for (int j = 0; j < 8; ++j) {
                b0[j] = (short)f2bf(wr0[ks * 32 + j]);
                b1[j] = (short)f2bf(wr1[ks * 32 + j]);
            }
            breg[ks][0] = b0; breg[ks][1] = b1;
        }
    }

    if (tid < 64) {
        int c = tid;
        int gr = (c >> 4) * 512 + p * 16 + (c & 15);
        bias[c] = bi[gr] + bh[gr];
    }
    for (int i = tid; i < 512; i += 256) ((float*)cst)[i] = 0.0f;

    // ---- placement discovery (deadlock-free: every owner writes its slot) ----
    if (tid < 64) {
        const unsigned* tp = tab + dir * 32 + (tid & 31);
        unsigned v;
        do { v = __hip_atomic_load(tp, __ATOMIC_RELAXED, __HIP_MEMORY_SCOPE_AGENT); } while (v == 0u);
        unsigned ref = __shfl(v, 0);
        int same = (__ballot(v == ref) == ~0ull) ? 1 : 0;
        if (tid == 0) mode_sh = same;
    }
    __syncthreads();
    const int fast = mode_sh;

    unsigned* flg = flags + (size_t)dir * 2048;
    unsigned short* hexd = h_ex + (size_t)dir * 2 * 16384;

    // ---- x prologue: DMA tiles for steps 0 and 1 into slots 0,1 (16 DMAs each) ----
    if (kh == 0) {
#pragma unroll
        for (int pre = 0; pre < 2; ++pre) {
            int t0 = dir ? (511 - pre) : pre;
            const unsigned short* src = Xb + (size_t)t0 * 16384 + nt * 8192 + ln * 8;
            unsigned short* lb = &xstage[pre][nt * 8192];
#pragma unroll
            for (int j = 0; j < 16; ++j) dma16(src + j * 512, lb + j * 512);
        }
    }

    int agent_poll = 0;
    int cur = 0;            // ring slot holding this step's x tile

    for (int s = 0; s < 512; ++s) {
        f32x4 acc00 = {0.f,0.f,0.f,0.f}, acc01 = {0.f,0.f,0.f,0.f};
        f32x4 acc10 = {0.f,0.f,0.f,0.f}, acc11 = {0.f,0.f,0.f,0.f};

        if (kh == 0) {
            if (s > 0) {
                // deferred out stores for step s-1 (acks retire during this step's GEMM)
                int pt = dir ? (512 - s) : (s - 1);
                int L = nt * 64 + ln; int b = L >> 2; int qd = L & 3;
                f32x4 hvv = *reinterpret_cast<const f32x4*>(&outbuf[(s - 1) & 1][b][qd * 4]);
                *reinterpret_cast<f32x4*>(&out[(size_t)b * 524288 + (size_t)pt * 1024
                                               + dir * 512 + p * 16 + qd * 4]) = hvv;
            } else {
                asm volatile("s_waitcnt vmcnt(16)" ::: "memory");   // slot0 DMA complete
            }
            // invariant for s>0: publish(s-1)'s vmcnt(16) already guaranteed slot `cur` ready
            __builtin_amdgcn_sched_barrier(0);
            const unsigned short* xs = &xstage[cur][0];
#pragma unroll
            for (int ks = 0; ks < 16; ++ks) {
                const unsigned short* ap = xs + (ks * 4 + q) * 256 + m15 * 8;
                short8 a0 = *reinterpret_cast<const short8*>(ap);
                short8 a1 = *reinterpret_cast<const short8*>(ap + 128);
                acc00 = __builtin_amdgcn_mfma_f32_16x16x32_bf16(a0, breg[ks][0], acc00, 0, 0, 0);
                acc01 = __builtin_amdgcn_mfma_f32_16x16x32_bf16(a0, breg[ks][1], acc01, 0, 0, 0);
                acc10 = __builtin_amdgcn_mfma_f32_16x16x32_bf16(a1, breg[ks][0], acc10, 0, 0, 0);
                acc11 = __builtin_amdgcn_mfma_f32_16x16x32_bf16(a1, breg[ks][1], acc11, 0, 0, 0);
            }
        } else if (fast) {
            // ---- h-recurrence, XCD-local L2 path ----
            if (s > 0) {
                const unsigned* fp = flg + (ln & 31);
                if (!agent_poll) {
                    int spins = 0;
                    for (;;) {
                        unsigned v;
                        asm volatile("global_load_dword %0, %1, off sc0\n\t"
                                     "s_waitcnt vmcnt(0)"
                                     : "=&v"(v) : "v"(fp) : "memory");
                        if (__ballot((int)(v >= (unsigned)s)) == ~0ull) break;
                        if (++spins > 20000) { agent_poll = 1; break; }
                        asm volatile("s_sleep 1" ::: "memory");     // decongest L2 flag line
                    }
                }
                if (agent_poll) {
                    for (;;) {
                        unsigned v = __hip_atomic_load(fp, __ATOMIC_RELAXED, __HIP_MEMORY_SCOPE_AGENT);
                        if (__ballot((int)(v >= (unsigned)s)) == ~0ull) break;
                    }
                }
                asm volatile("" ::: "memory");
            }
            const unsigned short* ab = hexd + (size_t)((s + 1) & 1) * 16384;
            i32x4 A0[16], A1[16];
#pragma unroll
            for (int ks = 0; ks < 16; ++ks) {
                const unsigned short* ap = ab + (size_t)(ks * 4 + q) * 256 + m15 * 8;
                asm volatile("global_load_dwordx4 %0, %2, off sc0\n\t"
                             "global_load_dwordx4 %1, %3, off sc0"
                             : "=&v"(A0[ks]), "=&v"(A1[ks])
                             : "v"(ap), "v"(ap + 128) : "memory");
            }
#pragma unroll
            for (int ks = 0; ks < 16; ++ks) {
                asm volatile("s_waitcnt vmcnt(%0)" :: "n"(30 - 2 * ks) : "memory");
                __builtin_amdgcn_sched_barrier(0);
                short8 a0 = __builtin_bit_cast(short8, A0[ks]);
                short8 a1 = __builtin_bit_cast(short8, A1[ks]);
                acc00 = __builtin_amdgcn_mfma_f32_16x16x32_bf16(a0, breg[ks][0], acc00, 0, 0, 0);
                acc01 = __builtin_amdgcn_mfma_f32_16x16x32_bf16(a0, breg[ks][1], acc01, 0, 0, 0);
                acc10 = __builtin_amdgcn_mfma_f32_16x16x32_bf16(a1, breg[ks][0], acc10, 0, 0, 0);
                acc11 = __builtin_amdgcn_mfma_f32_16x16x32_bf16(a1, breg[ks][1], acc11, 0, 0, 0);
            }
        } else {
            // ---- h-recurrence, fallback agent/LLC path ----
            if (s > 0) {
                const unsigned* fp = flg + (ln & 31);
                for (;;) {
                    unsigned v = __hip_atomic_load(fp, __ATOMIC_RELAXED, __HIP_MEMORY_SCOPE_AGENT);
                    if (__ballot((int)(v >= (unsigned)s)) == ~0ull) break;
                }
                asm volatile("" ::: "memory");
            }
            const unsigned* abase = reinterpret_cast<const unsigned*>(hexd + (size_t)((s + 1) & 1) * 16384);
#pragma unroll
            for (int ks = 0; ks < 16; ++ks) {
                const unsigned* ap = abase + ((ks * 4 + q) * 256 + m15 * 8) / 2;
                union { short8 s8; unsigned u[4]; } ua0, ua1;
#pragma unroll
                for (int w = 0; w < 4; ++w) {
                    ua0.u[w] = __hip_atomic_load(ap + w,      __ATOMIC_RELAXED, __HIP_MEMORY_SCOPE_AGENT);
                    ua1.u[w] = __hip_atomic_load(ap + 64 + w, __ATOMIC_RELAXED, __HIP_MEMORY_SCOPE_AGENT);
                }
                acc00 = __builtin_amdgcn_mfma_f32_16x16x32_bf16(ua0.s8, breg[ks][0], acc00, 0, 0, 0);
                acc01 = __builtin_amdgcn_mfma_f32_16x16x32_bf16(ua0.s8, breg[ks][1], acc01, 0, 0, 0);
                acc10 = __builtin_amdgcn_mfma_f32_16x16x32_bf16(ua1.s8, breg[ks][0], acc10, 0, 0, 0);
                acc11 = __builtin_amdgcn_mfma_f32_16x16x32_bf16(ua1.s8, breg[ks][1], acc11, 0, 0, 0);
            }
        }

        // ---- dump partial gates to LDS (C/D layout: col = ln&15, row = q*4 + r) ----
        {
            int rb = q * 4;
            int cb = nt * 32 + m15;
#pragma unroll
            for (int r = 0; r < 4; ++r) {
                gates[kh][rb + r][cb]           = acc00[r];
                gates[kh][rb + r][cb + 16]      = acc01[r];
                gates[kh][16 + rb + r][cb]      = acc10[r];
                gates[kh][16 + rb + r][cb + 16] = acc11[r];
            }
        }
        asm volatile("s_waitcnt lgkmcnt(0)" ::: "memory");
        __builtin_amdgcn_s_barrier();    // sync#1 (no vmem drain; DMAs ride across)
        __builtin_amdgcn_sched_barrier(0);

        // ---- gate math: each thread handles (b, j0) and (b, j0+1) ----
        {
            int b  = tid >> 3;
            int j0 = (tid & 7) * 2;
            float hv01[2];
#pragma unroll
            for (int u = 0; u < 2; ++u) {
                int j = j0 + u;
                float ig = gates[0][b][j]      + gates[1][b][j]      + bias[j];
                float fg = gates[0][b][16 + j] + gates[1][b][16 + j] + bias[16 + j];
                float gg = gates[0][b][32 + j] + gates[1][b][32 + j] + bias[32 + j];
                float og = gates[0][b][48 + j] + gates[1][b][48 + j] + bias[48 + j];
                float cn = sigf(fg) * cst[b][j] + sigf(ig) * tanhfast(gg);
                cst[b][j] = cn;
                hv01[u] = sigf(og) * tanhfast(cn);
            }
            *reinterpret_cast<float2*>(&outbuf[s & 1][b][j0]) = make_float2(hv01[0], hv01[1]);
            // packed 2xbf16 h store for the next step
            int hc0 = p * 16 + j0;
            unsigned pk = (unsigned)f2bf(hv01[0]) | ((unsigned)f2bf(hv01[1]) << 16);
            unsigned* dst = reinterpret_cast<unsigned*>(
                hexd + (size_t)(s & 1) * 16384 + (size_t)(hc0 >> 3) * 256 + b * 8 + (hc0 & 7));
            if (fast) {
                asm volatile("global_store_dword %0, %1, off sc0" :: "v"(dst), "v"(pk) : "memory");
            } else {
                __hip_atomic_store(dst, pk, __ATOMIC_RELAXED, __HIP_MEMORY_SCOPE_AGENT);
            }
        }

        // ---- x-waves: issue next-next tile DMA (stays in flight across barriers) ----
        if (kh == 0) {
            int nxt = cur + 2; if (nxt >= 3) nxt -= 3;
            int sp = s + 2; int tn = sp > 511 ? 511 : sp;
            int tx = dir ? (511 - tn) : tn;
            const unsigned short* src = Xb + (size_t)tx * 16384 + nt * 8192 + ln * 8;
            unsigned short* lb = &xstage[nxt][nt * 8192];
#pragma unroll
            for (int j = 0; j < 16; ++j) dma16(src + j * 512, lb + j * 512);
            // drain out-stores + h-store (older than the 16 fresh DMAs); keep DMAs in flight
            asm volatile("s_waitcnt vmcnt(16)" ::: "memory");
        } else {
            asm volatile("s_waitcnt vmcnt(0)" ::: "memory");   // h-store ack (L2)
        }
        asm volatile("s_waitcnt lgkmcnt(0)" ::: "memory");
        __builtin_amdgcn_s_barrier();    // sync#2
        __builtin_amdgcn_sched_barrier(0);
        if (tid == 0) {
            if (fast) {
                unsigned sv = (unsigned)(s + 1);
                asm volatile("global_store_dword %0, %1, off sc0" :: "v"(flg + p), "v"(sv) : "memory");
            } else {
                __hip_atomic_store(flg + p, (unsigned)(s + 1), __ATOMIC_RELAXED, __HIP_MEMORY_SCOPE_AGENT);
            }
        }
        cur = (cur + 1 == 3) ? 0 : cur + 1;
    }

    // ---- epilogue: step-511 out + final states (x-waves, 128 lanes) ----
    if (kh == 0) {
        int L = nt * 64 + ln; int b = L >> 2; int qd = L & 3;
        int tl = dir ? 0 : 511;
        f32x4 hvv = *reinterpret_cast<const f32x4*>(&outbuf[1][b][qd * 4]);
        *reinterpret_cast<f32x4*>(&out[(size_t)b * 524288 + (size_t)tl * 1024
                                       + dir * 512 + p * 16 + qd * 4]) = hvv;
        *reinterpret_cast<f32x4*>(&out[16777216 + dir * 16384 + b * 512 + p * 16 + qd * 4]) = hvv;
        f32x4 cvv = *reinterpret_cast<const f32x4*>(&cst[b][qd * 4]);
        *reinterpret_cast<f32x4*>(&out[16777216 + 32768 + dir * 16384 + b * 512 + p * 16 + qd * 4]) = cvv;
    }
}

extern "C" void kernel_launch(void* const* d_in, const int* in_sizes, int n_in,
                              void* d_out, int out_size, void* d_ws, size_t ws_size,
                              hipStream_t stream) {
    const float* X     = (const float*)d_in[0];
    const float* Wih_f = (const float*)d_in[1];
    const float* Whh_f = (const float*)d_in[2];
    const float* bih_f = (const float*)d_in[3];
    const float* bhh_f = (const float*)d_in[4];
    const float* Wih_b = (const float*)d_in[5];
    const float* Whh_b = (const float*)d_in[6];
    const float* bih_b = (const float*)d_in[7];
    const float* bhh_b = (const float*)d_in[8];
    float* out = (float*)d_out;

    unsigned short* Xb   = (unsigned short*)((char*)d_ws + XB_OFF);
    unsigned short* h_ex = (unsigned short*)((char*)d_ws + HEX_OFF);
    unsigned*       flg  = (unsigned*)((char*)d_ws + CTR_OFF);

    // zero h_ex (h_{-1}=0) + flags + placement table
    hipMemsetAsync((char*)d_ws + HEX_OFF, 0, (128ull + 64ull) << 10, stream);
    k_xpose<<<8192, 256, 0, stream>>>(X, Xb);
    // 256 blocks (1/CU): round-robin puts (blockIdx&7)==d on XCD d.
    k_bilstm<<<256, 256, 0, stream>>>(Wih_f, Whh_f, bih_f, bhh_f,
                                      Wih_b, Whh_b, bih_b, bhh_b,
                                      Xb, h_ex, flg, out);
}

// Round 5
// 2554.514 us; speedup vs baseline: 1.6559x; 1.3226x over previous
//
#include <hip/hip_runtime.h>
#include <hip/hip_bf16.h>

// Problem dims
#define BSZ 32
#define SSZ 512
#define ISZ 512
#define HSZ 512
// ws layout (bytes)
#define XB_OFF   0ull                       // [S][64 kc][32 b][8] ushort (bf16 bits) = 16 MB
#define HEX_OFF  (16ull << 20)              // [2 dir][2 buf][64 kc][32 b][8] ushort = 128 KB
#define CTR_OFF  (HEX_OFF + (128ull << 10)) // flags: [dir] stride 2048 dwords; 32 used per dir
#define XG_OFF   (32ull << 20)              // [dir][t][p][b][64] fp32 = 256 MB (precomputed x-gates)
#define WS_NEED  (XG_OFF + (256ull << 20))
// placement table at dword index 4096 in flags: [2 dir][32 p] = xcc+1

typedef __attribute__((ext_vector_type(8)))  short short8;
typedef __attribute__((ext_vector_type(4)))  float f32x4;
typedef __attribute__((ext_vector_type(4)))  unsigned short us4;
typedef __attribute__((ext_vector_type(4)))  int i32x4;

__device__ __forceinline__ unsigned short f2bf(float f) {
    union { float f; unsigned u; } v; v.f = f;
    unsigned r = v.u + 0x7fffu + ((v.u >> 16) & 1u);   // RNE
    return (unsigned short)(r >> 16);
}

__device__ __forceinline__ float sigf(float x) { return 1.0f / (1.0f + __expf(-x)); }
__device__ __forceinline__ float tanhfast(float x) {
    float a = fabsf(x);
    float e = __expf(-2.0f * a);
    float t = (1.0f - e) / (1.0f + e);
    return x < 0.0f ? -t : t;
}

// X [B][S][I] fp32 -> Xb [t][kc][b][8] bf16-bits (MFMA A-fragment friendly layout)
__global__ void k_xpose(const float* __restrict__ X, unsigned short* __restrict__ Xb) {
    int idx = blockIdx.x * 256 + threadIdx.x;     // 2^21 threads total
    int i4 = idx & 127;                           // float4 index along I
    int t  = (idx >> 7) & 511;
    int b  = idx >> 16;
    float4 v = reinterpret_cast<const float4*>(X)[idx];
    us4 o = { f2bf(v.x), f2bf(v.y), f2bf(v.z), f2bf(v.w) };
    *reinterpret_cast<us4*>(Xb + (size_t)t * 16384 + (size_t)(i4 >> 1) * 256 + b * 8 + (i4 & 1) * 4) = o;
}

// Precompute x-projection gates for ALL timesteps: xg[dir][t][p][b][64] fp32.
// Block = (dir, p, tq); wave wv = gate wv, cols p*16+0..15, full K=512.
// MFMA accumulation order identical to the in-loop version (bit-identical xproj).
__launch_bounds__(256, 1)
__global__ void k_xproj(const float* __restrict__ Wih_f, const float* __restrict__ Wih_b,
                        const unsigned short* __restrict__ Xb, float* __restrict__ xg)
{
    const int tid = threadIdx.x;
    const int bid = blockIdx.x;          // 256 blocks
    const int dir = bid & 1;
    const int p   = (bid >> 1) & 31;
    const int tq  = bid >> 6;            // 0..3 : t in [tq*128, tq*128+128)
    const int wv  = tid >> 6;            // gate index 0..3
    const int ln  = tid & 63;
    const int q   = ln >> 4;
    const int m15 = ln & 15;

    const float* Wih = dir ? Wih_b : Wih_f;

    short8 breg[16];
#pragma unroll
    for (int ks = 0; ks < 16; ++ks) {
        const float* wr = Wih + (size_t)(wv * 512 + p * 16 + m15) * 512 + ks * 32 + q * 8;
        short8 bb;
#pragma unroll
        for (int j = 0; j < 8; ++j) bb[j] = (short)f2bf(wr[j]);
        breg[ks] = bb;
    }

    for (int tt = 0; tt < 128; ++tt) {
        int t = tq * 128 + tt;
        const unsigned short* ab = Xb + (size_t)t * 16384;
        f32x4 acc0 = {0.f,0.f,0.f,0.f}, acc1 = {0.f,0.f,0.f,0.f};
#pragma unroll
        for (int ks = 0; ks < 16; ++ks) {
            const unsigned short* ap = ab + (ks * 4 + q) * 256 + m15 * 8;
            short8 a0 = *reinterpret_cast<const short8*>(ap);       // L1-dedup'd across waves
            short8 a1 = *reinterpret_cast<const short8*>(ap + 128);
            acc0 = __builtin_amdgcn_mfma_f32_16x16x32_bf16(a0, breg[ks], acc0, 0, 0, 0);
            acc1 = __builtin_amdgcn_mfma_f32_16x16x32_bf16(a1, breg[ks], acc1, 0, 0, 0);
        }
        float* ob = xg + (((size_t)(dir * 512 + t) * 32 + p) * 2048);
#pragma unroll
        for (int r = 0; r < 4; ++r) {
            ob[(q * 4 + r) * 64      + wv * 16 + m15] = acc0[r];
            ob[(16 + q * 4 + r) * 64 + wv * 16 + m15] = acc1[r];
        }
    }
}

// Recurrence-only kernel: 4 waves all do h@Whh^T, K-split (wave wv owns K [wv*128, +128)).
// Wave wv waits only on its 8 producer flags. x-gates read from precomputed xg.
__launch_bounds__(256, 1)
__global__ void k_bilstm2(const float* __restrict__ Whh_f, const float* __restrict__ Whh_b,
                          const float* __restrict__ bih_f, const float* __restrict__ bhh_f,
                          const float* __restrict__ bih_b, const float* __restrict__ bhh_b,
                          const float* __restrict__ xg,
                          unsigned short* h_ex, unsigned* flags, float* __restrict__ out)
{
    const int tid = threadIdx.x;
    const int grp = blockIdx.x & 7;
    if (grp >= 2) return;                // 256 blocks: XCD0 = dir0, XCD1 = dir1
    const int dir = grp;
    const int p   = blockIdx.x >> 3;     // 0..31 : owns h-cols [16p, 16p+16)
    const int wv  = tid >> 6;            // K-slice owner
    const int ln  = tid & 63;
    const int q   = ln >> 4;
    const int m15 = ln & 15;

    unsigned* tab = flags + 4096;
    {
        unsigned xcc;
        asm volatile("s_getreg_b32 %0, hwreg(20, 0, 32)" : "=s"(xcc));
        if (tid == 0)
            __hip_atomic_store(tab + dir * 32 + p, (xcc & 7u) + 1u,
                               __ATOMIC_RELAXED, __HIP_MEMORY_SCOPE_AGENT);
    }

    const float* Whh = dir ? Whh_b : Whh_f;
    const float* bi  = dir ? bih_b : bih_f;
    const float* bh  = dir ? bhh_b : bhh_f;

    __shared__ float gates[4][32][67];   // 4 K-partial planes
    __shared__ float cst[32][16];
    __shared__ float bias[64];
    __shared__ int   mode_sh;

    // weights: wave wv keeps all 4 gates for its K-slice: breg[ksl][g], ksl 0..3
    short8 breg[4][4];
#pragma unroll
    for (int ksl = 0; ksl < 4; ++ksl)
#pragma unroll
        for (int g = 0; g < 4; ++g) {
            const float* wr = Whh + (size_t)(g * 512 + p * 16 + m15) * 512
                                  + wv * 128 + ksl * 32 + q * 8;
            short8 bb;
#pragma unroll
            for (int j = 0; j < 8; ++j) bb[j] = (short)f2bf(wr[j]);
            breg[ksl][g] = bb;
        }

    if (tid < 64) {
        int c = tid;
        int gr = (c >> 4) * 512 + p * 16 + (c & 15);
        bias[c] = bi[gr] + bh[gr];
    }
    for (int i = tid; i < 512; i += 256) ((float*)cst)[i] = 0.0f;

    // placement discovery (deadlock-free: every owner writes its slot)
    if (tid < 64) {
        const unsigned* tp = tab + dir * 32 + (tid & 31);
        unsigned v;
        do { v = __hip_atomic_load(tp, __ATOMIC_RELAXED, __HIP_MEMORY_SCOPE_AGENT); } while (v == 0u);
        unsigned ref = __shfl(v, 0);
        int same = (__ballot(v == ref) == ~0ull) ? 1 : 0;
        if (tid == 0) mode_sh = same;
    }
    __syncthreads();
    const int fast = mode_sh;

    unsigned* flg = flags + (size_t)dir * 2048;
    unsigned short* hexd = h_ex + (size_t)dir * 2 * 16384;

    const int b  = tid >> 3;
    const int j0 = (tid & 7) * 2;

    int agent_poll = 0;

    for (int s = 0; s < 512; ++s) {
        const int t = dir ? (511 - s) : s;
        const float* xgp = xg + ((size_t)(dir * 512 + t) * 32 + p) * 2048 + b * 64 + j0;

        f32x4 acc[4][2];
#pragma unroll
        for (int g = 0; g < 4; ++g) { acc[g][0] = {0.f,0.f,0.f,0.f}; acc[g][1] = {0.f,0.f,0.f,0.f}; }
        float2 xgv[4];

        if (fast) {
            if (s > 0) {
                // wave wv needs only its 8 K-slice producers: flags [wv*8, wv*8+8)
                const unsigned* fp = flg + wv * 8 + (ln & 7);
                if (!agent_poll) {
                    int spins = 0;
                    for (;;) {
                        unsigned v;
                        asm volatile("global_load_dword %0, %1, off sc0\n\t"
                                     "s_waitcnt vmcnt(0)"
                                     : "=&v"(v) : "v"(fp) : "memory");
                        if (__ballot((int)(v >= (unsigned)s)) == ~0ull) break;
                        if (++spins > 20000) { agent_poll = 1; break; }
                    }
                }
                if (agent_poll) {
                    for (;;) {
                        unsigned v = __hip_atomic_load(fp, __ATOMIC_RELAXED, __HIP_MEMORY_SCOPE_AGENT);
                        if (__ballot((int)(v >= (unsigned)s)) == ~0ull) break;
                    }
                }
                asm volatile("" ::: "memory");
            }
            // h K-slice loads (8 × dwordx4 sc0), then xg loads (4 × dwordx2, cached)
            const unsigned short* ab = hexd + (size_t)((s + 1) & 1) * 16384 + wv * 4096;
            i32x4 A0[4], A1[4];
#pragma unroll
            for (int ksl = 0; ksl < 4; ++ksl) {
                const unsigned short* ap = ab + (ksl * 4 + q) * 256 + m15 * 8;
                asm volatile("global_load_dwordx4 %0, %2, off sc0\n\t"
                             "global_load_dwordx4 %1, %3, off sc0"
                             : "=&v"(A0[ksl]), "=&v"(A1[ksl])
                             : "v"(ap), "v"(ap + 128) : "memory");
            }
#pragma unroll
            for (int g = 0; g < 4; ++g)
                asm volatile("global_load_dwordx2 %0, %1, off"
                             : "=v"(xgv[g]) : "v"(xgp + g * 16) : "memory");
            // counted waits: ops = 8 h-loads then 4 xg loads (in-order retire)
#pragma unroll
            for (int ksl = 0; ksl < 4; ++ksl) {
                asm volatile("s_waitcnt vmcnt(%0)" :: "n"(10 - 2 * ksl) : "memory");
                __builtin_amdgcn_sched_barrier(0);   // rule #18
                short8 a0 = __builtin_bit_cast(short8, A0[ksl]);
                short8 a1 = __builtin_bit_cast(short8, A1[ksl]);
#pragma unroll
                for (int g = 0; g < 4; ++g) {
                    acc[g][0] = __builtin_amdgcn_mfma_f32_16x16x32_bf16(a0, breg[ksl][g], acc[g][0], 0, 0, 0);
                    acc[g][1] = __builtin_amdgcn_mfma_f32_16x16x32_bf16(a1, breg[ksl][g], acc[g][1], 0, 0, 0);
                }
            }
        } else {
            // fallback agent/LLC path (all-32 flag wait)
            if (s > 0) {
                const unsigned* fp = flg + (ln & 31);
                for (;;) {
                    unsigned v = __hip_atomic_load(fp, __ATOMIC_RELAXED, __HIP_MEMORY_SCOPE_AGENT);
                    if (__ballot((int)(v >= (unsigned)s)) == ~0ull) break;
                }
                asm volatile("" ::: "memory");
            }
            const unsigned* abase = reinterpret_cast<const unsigned*>(
                hexd + (size_t)((s + 1) & 1) * 16384 + wv * 4096);
#pragma unroll
            for (int ksl = 0; ksl < 4; ++ksl) {
                const unsigned* ap = abase + ((ksl * 4 + q) * 256 + m15 * 8) / 2;
                union { short8 s8; unsigned u[4]; } ua0, ua1;
#pragma unroll
                for (int w = 0; w < 4; ++w) {
                    ua0.u[w] = __hip_atomic_load(ap + w,      __ATOMIC_RELAXED, __HIP_MEMORY_SCOPE_AGENT);
                    ua1.u[w] = __hip_atomic_load(ap + 64 + w, __ATOMIC_RELAXED, __HIP_MEMORY_SCOPE_AGENT);
                }
#pragma unroll
                for (int g = 0; g < 4; ++g) {
                    acc[g][0] = __builtin_amdgcn_mfma_f32_16x16x32_bf16(ua0.s8, breg[ksl][g], acc[g][0], 0, 0, 0);
                    acc[g][1] = __builtin_amdgcn_mfma_f32_16x16x32_bf16(ua1.s8, breg[ksl][g], acc[g][1], 0, 0, 0);
                }
            }
#pragma unroll
            for (int g = 0; g < 4; ++g)
                xgv[g] = *reinterpret_cast<const float2*>(xgp + g * 16);
        }

        // dump K-partial gates (plane = wv); C/D: col = ln&15, row = q*4 + r
#pragma unroll
        for (int g = 0; g < 4; ++g)
#pragma unroll
            for (int r = 0; r < 4; ++r) {
                gates[wv][q * 4 + r][g * 16 + m15]      = acc[g][0][r];
                gates[wv][16 + q * 4 + r][g * 16 + m15] = acc[g][1][r];
            }
        asm volatile("s_waitcnt lgkmcnt(0)" ::: "memory");
        __builtin_amdgcn_s_barrier();    // sync#1
        asm volatile("s_waitcnt vmcnt(0)" ::: "memory");   // xg loads landed
        __builtin_amdgcn_sched_barrier(0);                 // rule #18

        // gate math: thread (b, j0), cols j0 and j0+1
        {
            float hv01[2], cn01[2];
#pragma unroll
            for (int u = 0; u < 2; ++u) {
                int j = j0 + u;
                float ig = gates[0][b][j]      + gates[1][b][j]      + gates[2][b][j]      + gates[3][b][j]
                         + (u ? xgv[0].y : xgv[0].x) + bias[j];
                float fg = gates[0][b][16 + j] + gates[1][b][16 + j] + gates[2][b][16 + j] + gates[3][b][16 + j]
                         + (u ? xgv[1].y : xgv[1].x) + bias[16 + j];
                float gg = gates[0][b][32 + j] + gates[1][b][32 + j] + gates[2][b][32 + j] + gates[3][b][32 + j]
                         + (u ? xgv[2].y : xgv[2].x) + bias[32 + j];
                float og = gates[0][b][48 + j] + gates[1][b][48 + j] + gates[2][b][48 + j] + gates[3][b][48 + j]
                         + (u ? xgv[3].y : xgv[3].x) + bias[48 + j];
                float cn = sigf(fg) * cst[b][j] + sigf(ig) * tanhfast(gg);
                cst[b][j] = cn;
                hv01[u] = sigf(og) * tanhfast(cn);
                cn01[u] = cn;
            }
            // packed 2xbf16 h store for the next step
            int hc0 = p * 16 + j0;
            unsigned pk = (unsigned)f2bf(hv01[0]) | ((unsigned)f2bf(hv01[1]) << 16);
            unsigned* dst = reinterpret_cast<unsigned*>(
                hexd + (size_t)(s & 1) * 16384 + (size_t)(hc0 >> 3) * 256 + b * 8 + (hc0 & 7));
            if (fast) {
                asm volatile("global_store_dword %0, %1, off sc0" :: "v"(dst), "v"(pk) : "memory");
            } else {
                __hip_atomic_store(dst, pk, __ATOMIC_RELAXED, __HIP_MEMORY_SCOPE_AGENT);
            }
            // out stores (acks overlap publish drain + next poll)
            *reinterpret_cast<float2*>(&out[(size_t)b * 524288 + (size_t)t * 1024
                                            + dir * 512 + hc0]) = make_float2(hv01[0], hv01[1]);
            if (s == 511) {
                *reinterpret_cast<float2*>(&out[16777216 + dir * 16384 + b * 512 + hc0])
                    = make_float2(hv01[0], hv01[1]);
                *reinterpret_cast<float2*>(&out[16777216 + 32768 + dir * 16384 + b * 512 + hc0])
                    = make_float2(cn01[0], cn01[1]);
            }
        }

        // publish: drain h store (+ out stores), then flag
        asm volatile("s_waitcnt vmcnt(0)" ::: "memory");
        asm volatile("s_waitcnt lgkmcnt(0)" ::: "memory");
        __builtin_amdgcn_s_barrier();    // sync#2
        if (tid == 0) {
            if (fast) {
                unsigned sv = (unsigned)(s + 1);
                asm volatile("global_store_dword %0, %1, off sc0" :: "v"(flg + p), "v"(sv) : "memory");
            } else {
                __hip_atomic_store(flg + p, (unsigned)(s + 1), __ATOMIC_RELAXED, __HIP_MEMORY_SCOPE_AGENT);
            }
        }
    }
}

// ---------------- Fallback: Round-1 kernel verbatim (used if ws too small) ----------------
__launch_bounds__(256, 1)
__global__ void k_bilstm_fb(const float* __restrict__ Wih_f, const float* __restrict__ Whh_f,
                            const float* __restrict__ bih_f, const float* __restrict__ bhh_f,
                            const float* __restrict__ Wih_b, const float* __restrict__ Whh_b,
                            const float* __restrict__ bih_b, const float* __restrict__ bhh_b,
                            const unsigned short* __restrict__ Xb,
                            unsigned short* h_ex, unsigned* flags, float* __restrict__ out)
{
    const int tid = threadIdx.x;
    const int grp = blockIdx.x & 7;
    if (grp >= 2) return;
    const int dir = grp;
    const int p   = blockIdx.x >> 3;
    const int wv  = tid >> 6;
    const int ln  = tid & 63;
    const int kh  = wv >> 1;
    const int nt  = wv & 1;
    const int q   = ln >> 4;
    const int m15 = ln & 15;

    unsigned* tab = flags + 4096;
    {
        unsigned xcc;
        asm volatile("s_getreg_b32 %0, hwreg(20, 0, 32)" : "=s"(xcc));
        if (tid == 0)
            __hip_atomic_store(tab + dir * 32 + p, (xcc & 7u) + 1u,
                               __ATOMIC_RELAXED, __HIP_MEMORY_SCOPE_AGENT);
    }

    const float* Wsel = kh ? (dir ? Whh_b : Whh_f) : (dir ? Wih_b : Wih_f);
    const float* bi   = dir ? bih_b : bih_f;
    const float* bh   = dir ? bhh_b : bhh_f;

    __shared__ float gates[2][32][67];
    __shared__ float cst[32][16];
    __shared__ float bias[64];
    __shared__ int   mode_sh;

    short8 breg[16][2];
    {
        const float* wr0 = Wsel + (size_t)((nt * 2 + 0) * 512 + p * 16 + m15) * 512 + q * 8;
        const float* wr1 = Wsel + (size_t)((nt * 2 + 1) * 512 + p * 16 + m15) * 512 + q * 8;
#pragma unroll
        for (int ks = 0; ks < 16; ++ks) {
            short8 b0, b1;
#pragma unroll
            for (int j = 0; j < 8; ++j) {
                b0[j] = (short)f2bf(wr0[ks * 32 + j]);
                b1[j] = (short)f2bf(wr1[ks * 32 + j]);
            }
            breg[ks][0] = b0; breg[ks][1] = b1;
        }
    }

    if (tid < 64) {
        int c = tid;
        int gr = (c >> 4) * 512 + p * 16 + (c & 15);
        bias[c] = bi[gr] + bh[gr];
    }
    for (int i = tid; i < 512; i += 256) ((float*)cst)[i] = 0.0f;

    if (tid < 64) {
        const unsigned* tp = tab + dir * 32 + (tid & 31);
        unsigned v;
        do { v = __hip_atomic_load(tp, __ATOMIC_RELAXED, __HIP_MEMORY_SCOPE_AGENT); } while (v == 0u);
        unsigned ref = __shfl(v, 0);
        int same = (__ballot(v == ref) == ~0ull) ? 1 : 0;
        if (tid == 0) mode_sh = same;
    }
    __syncthreads();
    const int fast = mode_sh;

    unsigned* flg = flags + (size_t)dir * 2048;
    unsigned short* hexd = h_ex + (size_t)dir * 2 * 16384;

    int agent_poll = 0;

    for (int s = 0; s < 512; ++s) {
        const int t = dir ? (511 - s) : s;
        f32x4 acc00 = {0.f,0.f,0.f,0.f}, acc01 = {0.f,0.f,0.f,0.f};
        f32x4 acc10 = {0.f,0.f,0.f,0.f}, acc11 = {0.f,0.f,0.f,0.f};

        if (kh == 0) {
            const unsigned short* abase = Xb + (size_t)t * 16384;
#pragma unroll
            for (int ks = 0; ks < 16; ++ks) {
                const unsigned short* ap = abase + (size_t)(ks * 4 + q) * 256 + m15 * 8;
                short8 a0 = *reinterpret_cast<const short8*>(ap);
                short8 a1 = *reinterpret_cast<const short8*>(ap + 128);
                acc00 = __builtin_amdgcn_mfma_f32_16x16x32_bf16(a0, breg[ks][0], acc00, 0, 0, 0);
                acc01 = __builtin_amdgcn_mfma_f32_16x16x32_bf16(a0, breg[ks][1], acc01, 0, 0, 0);
                acc10 = __builtin_amdgcn_mfma_f32_16x16x32_bf16(a1, breg[ks][0], acc10, 0, 0, 0);
                acc11 = __builtin_amdgcn_mfma_f32_16x16x32_bf16(a1, breg[ks][1], acc11, 0, 0, 0);
            }
        } else if (fast) {
            if (s > 0) {
                const unsigned* fp = flg + (ln & 31);
                if (!agent_poll) {
                    int spins = 0;
                    for (;;) {
                        unsigned v;
                        asm volatile("global_load_dword %0, %1, off sc0\n\t"
                                     "s_waitcnt vmcnt(0)"
                                     : "=&v"(v) : "v"(fp) : "memory");
                        if (__ballot((int)(v >= (unsigned)s)) == ~0ull) break;
                        if (++spins > 20000) { agent_poll = 1; break; }
                    }
                }
                if (agent_poll) {
                    for (;;) {
                        unsigned v = __hip_atomic_load(fp, __ATOMIC_RELAXED, __HIP_MEMORY_SCOPE_AGENT);
                        if (__ballot((int)(v >= (unsigned)s)) == ~0ull) break;
                    }
                }
                asm volatile("" ::: "memory");
            }
            const unsigned short* ab = hexd + (size_t)((s + 1) & 1) * 16384;
            i32x4 A0[16], A1[16];
#pragma unroll
            for (int ks = 0; ks < 16; ++ks) {
                const unsigned short* ap = ab + (size_t)(ks * 4 + q) * 256 + m15 * 8;
                asm volatile("global_load_dwordx4 %0, %2, off sc0\n\t"
                             "global_load_dwordx4 %1, %3, off sc0"
                             : "=&v"(A0[ks]), "=&v"(A1[ks])
                             : "v"(ap), "v"(ap + 128) : "memory");
            }
#pragma unroll
            for (int ks = 0; ks < 16; ++ks) {
                asm volatile("s_waitcnt vmcnt(%0)" :: "n"(30 - 2 * ks) : "memory");
                __builtin_amdgcn_sched_barrier(0);
                short8 a0 = __builtin_bit_cast(short8, A0[ks]);
                short8 a1 = __builtin_bit_cast(short8, A1[ks]);
                acc00 = __builtin_amdgcn_mfma_f32_16x16x32_bf16(a0, breg[ks][0], acc00, 0, 0, 0);
                acc01 = __builtin_amdgcn_mfma_f32_16x16x32_bf16(a0, breg[ks][1], acc01, 0, 0, 0);
                acc10 = __builtin_amdgcn_mfma_f32_16x16x32_bf16(a1, breg[ks][0], acc10, 0, 0, 0);
                acc11 = __builtin_amdgcn_mfma_f32_16x16x32_bf16(a1, breg[ks][1], acc11, 0, 0, 0);
            }
        } else {
            if (s > 0) {
                const unsigned* fp = flg + (ln & 31);
                for (;;) {
                    unsigned v = __hip_atomic_load(fp, __ATOMIC_RELAXED, __HIP_MEMORY_SCOPE_AGENT);
                    if (__ballot((int)(v >= (unsigned)s)) == ~0ull) break;
                }
                asm volatile("" ::: "memory");
            }
            const unsigned* abase = reinterpret_cast<const unsigned*>(hexd + (size_t)((s + 1) & 1) * 16384);
#pragma unroll
            for (int ks = 0; ks < 16; ++ks) {
                const unsigned* ap = abase + ((ks * 4 + q) * 256 + m15 * 8) / 2;
                union { short8 s8; unsigned u[4]; } ua0, ua1;
#pragma unroll
                for (int w = 0; w < 4; ++w) {
                    ua0.u[w] = __hip_atomic_load(ap + w,      __ATOMIC_RELAXED, __HIP_MEMORY_SCOPE_AGENT);
                    ua1.u[w] = __hip_atomic_load(ap + 64 + w, __ATOMIC_RELAXED, __HIP_MEMORY_SCOPE_AGENT);
                }
                acc00 = __builtin_amdgcn_mfma_f32_16x16x32_bf16(ua0.s8, breg[ks][0], acc00, 0, 0, 0);
                acc01 = __builtin_amdgcn_mfma_f32_16x16x32_bf16(ua0.s8, breg[ks][1], acc01, 0, 0, 0);
                acc10 = __builtin_amdgcn_mfma_f32_16x16x32_bf16(ua1.s8, breg[ks][0], acc10, 0, 0, 0);
                acc11 = __builtin_amdgcn_mfma_f32_16x16x32_bf16(ua1.s8, breg[ks][1], acc11, 0, 0, 0);
            }
        }

        {
            int rb = q * 4;
            int cb = nt * 32 + m15;
#pragma unroll
            for (int r = 0; r < 4; ++r) {
                gates[kh][rb + r][cb]           = acc00[r];
                gates[kh][rb + r][cb + 16]      = acc01[r];
                gates[kh][16 + rb + r][cb]      = acc10[r];
                gates[kh][16 + rb + r][cb + 16] = acc11[r];
            }
        }
        __syncthreads();

        int b  = tid >> 3;
        int j0 = (tid & 7) * 2;
        float hv01[2], cn01[2];
        {
#pragma unroll
            for (int u = 0; u < 2; ++u) {
                int j = j0 + u;
                float ig = gates[0][b][j]      + gates[1][b][j]      + bias[j];
                float fg = gates[0][b][16 + j] + gates[1][b][16 + j] + bias[16 + j];
                float gg = gates[0][b][32 + j] + gates[1][b][32 + j] + bias[32 + j];
                float og = gates[0][b][48 + j] + gates[1][b][48 + j] + bias[48 + j];
                float cn = sigf(fg) * cst[b][j] + sigf(ig) * tanhfast(gg);
                cst[b][j] = cn;
                float hv = sigf(og) * tanhfast(cn);
                hv01[u] = hv; cn01[u] = cn;
            }
            int hc0 = p * 16 + j0;
            unsigned pk = (unsigned)f2bf(hv01[0]) | ((unsigned)f2bf(hv01[1]) << 16);
            unsigned* dst = reinterpret_cast<unsigned*>(
                hexd + (size_t)(s & 1) * 16384 + (size_t)(hc0 >> 3) * 256 + b * 8 + (hc0 & 7));
            if (fast) {
                asm volatile("global_store_dword %0, %1, off sc0" :: "v"(dst), "v"(pk) : "memory");
            } else {
                __hip_atomic_store(dst, pk, __ATOMIC_RELAXED, __HIP_MEMORY_SCOPE_AGENT);
            }
        }

        asm volatile("s_waitcnt vmcnt(0)" ::: "memory");
        __syncthreads();
        if (tid == 0) {
            if (fast) {
                unsigned sv = (unsigned)(s + 1);
                asm volatile("global_store_dword %0, %1, off sc0" :: "v"(flg + p), "v"(sv) : "memory");
            } else {
                __hip_atomic_store(flg + p, (unsigned)(s + 1), __ATOMIC_RELAXED, __HIP_MEMORY_SCOPE_AGENT);
            }
        }

#pragma unroll
        for (int u = 0; u < 2; ++u) {
            int hc = p * 16 + j0 + u;
            out[(size_t)b * (512 * 1024) + (size_t)t * 1024 + dir * 512 + hc] = hv01[u];
            if (s == 511) {
                out[16777216 + dir * 16384 + b * 512 + hc] = hv01[u];
                out[16777216 + 32768 + dir * 16384 + b * 512 + hc] = cn01[u];
            }
        }
    }
}

extern "C" void kernel_launch(void* const* d_in, const int* in_sizes, int n_in,
                              void* d_out, int out_size, void* d_ws, size_t ws_size,
                              hipStream_t stream) {
    const float* X     = (const float*)d_in[0];
    const float* Wih_f = (const float*)d_in[1];
    const float* Whh_f = (const float*)d_in[2];
    const float* bih_f = (const float*)d_in[3];
    const float* bhh_f = (const float*)d_in[4];
    const float* Wih_b = (const float*)d_in[5];
    const float* Whh_b = (const float*)d_in[6];
    const float* bih_b = (const float*)d_in[7];
    const float* bhh_b = (const float*)d_in[8];
    float* out = (float*)d_out;

    unsigned short* Xb   = (unsigned short*)((char*)d_ws + XB_OFF);
    unsigned short* h_ex = (unsigned short*)((char*)d_ws + HEX_OFF);
    unsigned*       flg  = (unsigned*)((char*)d_ws + CTR_OFF);
    float*          xg   = (float*)((char*)d_ws + XG_OFF);

    // zero h_ex (h_{-1}=0) + flags + placement table
    hipMemsetAsync((char*)d_ws + HEX_OFF, 0, (128ull + 64ull) << 10, stream);
    k_xpose<<<8192, 256, 0, stream>>>(X, Xb);

    if (ws_size >= WS_NEED) {
        k_xproj<<<256, 256, 0, stream>>>(Wih_f, Wih_b, Xb, xg);
        k_bilstm2<<<256, 256, 0, stream>>>(Whh_f, Whh_b, bih_f, bhh_f, bih_b, bhh_b,
                                           xg, h_ex, flg, out);
    } else {
        k_bilstm_fb<<<256, 256, 0, stream>>>(Wih_f, Whh_f, bih_f, bhh_f,
                                             Wih_b, Whh_b, bih_b, bhh_b,
                                             Xb, h_ex, flg, out);
    }
}